// Round 4
// baseline (93.811 us; speedup 1.0000x reference)
//
#include <hip/hip_runtime.h>
#include <hip/hip_bf16.h>

typedef __attribute__((ext_vector_type(4))) float f32x4;
typedef __attribute__((ext_vector_type(8))) short bf16x8;

#define AS1 __attribute__((address_space(1)))
#define AS3 __attribute__((address_space(3)))

__device__ __forceinline__ unsigned short f2bf(float f) {
    unsigned int u = __float_as_uint(f);
    u = (u + 0x7FFFu + ((u >> 16) & 1u)) >> 16;
    return (unsigned short)u;
}

__device__ __forceinline__ float bf2f(unsigned short u) {
    return __uint_as_float(((unsigned int)u) << 16);
}

// Fused conversion: blocks [0,12500) convert features (200000*128 f32 -> bf16),
// blocks [12500,12628) convert W1|W2 (2*128*256).
__global__ __launch_bounds__(256) void cvt_fused(const float* __restrict__ feat,
                                                 const float* __restrict__ W1,
                                                 const float* __restrict__ W2,
                                                 unsigned short* __restrict__ featb,
                                                 unsigned short* __restrict__ W1b,
                                                 unsigned short* __restrict__ W2b) {
    if (blockIdx.x < 12500) {
        size_t i = ((size_t)blockIdx.x * 256 + threadIdx.x) * 8;
        float4 a = *(const float4*)(feat + i);
        float4 b = *(const float4*)(feat + i + 4);
        bf16x8 o;
        o[0] = (short)f2bf(a.x); o[1] = (short)f2bf(a.y);
        o[2] = (short)f2bf(a.z); o[3] = (short)f2bf(a.w);
        o[4] = (short)f2bf(b.x); o[5] = (short)f2bf(b.y);
        o[6] = (short)f2bf(b.z); o[7] = (short)f2bf(b.w);
        *(bf16x8*)(featb + i) = o;
    } else {
        int i = (blockIdx.x - 12500) * 256 + threadIdx.x;   // [0, 32768)
        W1b[i] = f2bf(W1[i]);
        W2b[i] = f2bf(W2[i]);
    }
}

// Fused layer with async gather staging:
//   out[m] = relu([src[self[m]] | mean_s src[neigh[m][s]]] @ W^T)
// 16 rows/block, 256 threads. 160 neighbor rows DMA'd to LDS via
// global_load_lds (40 x 1KB instructions, per-lane gather addresses),
// self rows via 1 reg load/thread. K=256, N=128.
template<bool OUT_BF16>
__global__ __launch_bounds__(256, 3)
void sage_layer_dma(const unsigned short* __restrict__ src,   // [*,128] bf16
                    const unsigned short* __restrict__ Wb,    // [128][256] bf16 row-major
                    const int* __restrict__ self_idx,
                    const int* __restrict__ neigh_idx,
                    void* __restrict__ out_v) {
    __shared__ unsigned short stage[160 * 128];   // 40960 B: neighbor rows, row-major 256B
    __shared__ unsigned short As[16][264];        // 8448 B: [self|agg], +8 pad (row 528B)

    const int t = threadIdx.x;
    const int lane = t & 63;
    const int w = t >> 6;
    const int rowBase = blockIdx.x * 16;

    // ---- Issue phase: no barrier needed, indices read straight from global ----
    // Per-wave: preload 10 neighbor-row indices (4 distinct per instr, lane>>4 picks).
    const int w10 = w * 10;
    int nri[10];
    #pragma unroll
    for (int li = 0; li < 10; ++li)
        nri[li] = neigh_idx[rowBase * 10 + (w10 + li) * 4 + (lane >> 4)];

    // Self row: one 16B reg load per thread (r = t>>4, chunk c = t&15).
    const int sr = self_idx[rowBase + (t >> 4)];
    bf16x8 selfv = *(const bf16x8*)(src + (size_t)sr * 128 + (t & 15) * 8);

    // 10 async 1KB gather-DMAs per wave: instr i stages neighbor rows 4i..4i+3.
    #pragma unroll
    for (int li = 0; li < 10; ++li) {
        const int i = w10 + li;
        const unsigned short* gp = src + (size_t)nri[li] * 128 + (lane & 15) * 8;
        unsigned short* lp = &stage[i * 512];
        __builtin_amdgcn_global_load_lds((const AS1 void*)gp, (AS3 void*)lp, 16, 0, 0);
    }

    asm volatile("s_waitcnt vmcnt(0)" ::: "memory");
    __syncthreads();

    // ---- Sum phase: thread (r = t>>4, c = t&15) reduces 10 neighbor chunks ----
    {
        const int r = t >> 4;
        const int co = (t & 15) * 8;
        float s[8];
        #pragma unroll
        for (int e = 0; e < 8; ++e) s[e] = 0.f;
        #pragma unroll
        for (int j = 0; j < 10; ++j) {
            bf16x8 v = *(const bf16x8*)&stage[(r * 10 + j) * 128 + co];
            #pragma unroll
            for (int e = 0; e < 8; ++e) s[e] += bf2f((unsigned short)v[e]);
        }
        bf16x8 o;
        #pragma unroll
        for (int e = 0; e < 8; ++e) o[e] = (short)f2bf(s[e] * 0.1f);
        *(bf16x8*)&As[r][co] = selfv;
        *(bf16x8*)&As[r][128 + co] = o;
    }
    __syncthreads();

    // ---- MFMA: wave w -> rows 0..15, cols w*32..w*32+32. K=256 via 8 steps ----
    const int cols32 = w * 32;
    const int arow = lane & 15;
    const int ko = (lane >> 4) * 8;
    const int ncol = lane & 15;

    f32x4 acc[2];
    acc[0] = (f32x4){0.f, 0.f, 0.f, 0.f};
    acc[1] = (f32x4){0.f, 0.f, 0.f, 0.f};

    #pragma unroll
    for (int kk = 0; kk < 8; ++kk) {
        bf16x8 af = *(const bf16x8*)&As[arow][kk * 32 + ko];
        #pragma unroll
        for (int ct = 0; ct < 2; ++ct) {
            const unsigned short* wp = Wb + (size_t)(cols32 + ct * 16 + ncol) * 256 + kk * 32 + ko;
            bf16x8 bf = *(const bf16x8*)wp;
            acc[ct] = __builtin_amdgcn_mfma_f32_16x16x32_bf16(af, bf, acc[ct], 0, 0, 0);
        }
    }

    // C/D: col = lane&15, row = (lane>>4)*4 + r
    const int mr = rowBase + (lane >> 4) * 4;
    if (OUT_BF16) {
        unsigned short* out = (unsigned short*)out_v;
        #pragma unroll
        for (int ct = 0; ct < 2; ++ct) {
            #pragma unroll
            for (int r = 0; r < 4; ++r) {
                out[(size_t)(mr + r) * 128 + cols32 + ct * 16 + ncol] = f2bf(fmaxf(acc[ct][r], 0.f));
            }
        }
    } else {
        float* out = (float*)out_v;
        #pragma unroll
        for (int ct = 0; ct < 2; ++ct) {
            #pragma unroll
            for (int r = 0; r < 4; ++r) {
                out[(size_t)(mr + r) * 128 + cols32 + ct * 16 + ncol] = fmaxf(acc[ct][r], 0.f);
            }
        }
    }
}

// ---- Fallback (f32-source) layer kernel, used only if ws is too small ----
template<bool SRC_BF16, bool OUT_BF16>
__global__ __launch_bounds__(256, 2)
void sage_layer(const void* __restrict__ src_v,
                const unsigned short* __restrict__ Wb,
                const int* __restrict__ self_idx,
                const int* __restrict__ neigh_idx,
                void* __restrict__ out_v) {
    __shared__ unsigned short As[64][264];
    __shared__ int sIdx[64];
    __shared__ int nIdx[64][10];

    const int t = threadIdx.x;
    const int rowBase = blockIdx.x * 64;

    if (t < 64) sIdx[t] = self_idx[rowBase + t];
    for (int i = t; i < 640; i += 256) nIdx[i / 10][i % 10] = neigh_idx[rowBase * 10 + i];
    __syncthreads();

    #pragma unroll
    for (int it = 0; it < 16; ++it) {
        int c = it * 256 + t;
        int row = c >> 6;
        int cc = c & 63;
        float4 v;
        if (cc < 32) {
            if constexpr (SRC_BF16) {
                ushort4 u = *(const ushort4*)((const unsigned short*)src_v + (size_t)sIdx[row] * 128 + cc * 4);
                v.x = bf2f(u.x); v.y = bf2f(u.y); v.z = bf2f(u.z); v.w = bf2f(u.w);
            } else {
                v = *(const float4*)((const float*)src_v + (size_t)sIdx[row] * 128 + cc * 4);
            }
        } else {
            int fo = (cc - 32) * 4;
            float sx = 0.f, sy = 0.f, sz = 0.f, sw = 0.f;
            #pragma unroll
            for (int sn = 0; sn < 10; ++sn) {
                float4 x;
                if constexpr (SRC_BF16) {
                    ushort4 u = *(const ushort4*)((const unsigned short*)src_v + (size_t)nIdx[row][sn] * 128 + fo);
                    x.x = bf2f(u.x); x.y = bf2f(u.y); x.z = bf2f(u.z); x.w = bf2f(u.w);
                } else {
                    x = *(const float4*)((const float*)src_v + (size_t)nIdx[row][sn] * 128 + fo);
                }
                sx += x.x; sy += x.y; sz += x.z; sw += x.w;
            }
            v.x = sx * 0.1f; v.y = sy * 0.1f; v.z = sz * 0.1f; v.w = sw * 0.1f;
        }
        ushort4 o;
        o.x = f2bf(v.x); o.y = f2bf(v.y); o.z = f2bf(v.z); o.w = f2bf(v.w);
        *(ushort4*)&As[row][cc * 4] = o;
    }
    __syncthreads();

    const int lane = t & 63;
    const int w = t >> 6;
    const int arow = w * 16 + (lane & 15);
    const int ko = (lane >> 4) * 8;
    const int ncol = lane & 15;

    f32x4 acc[8];
    #pragma unroll
    for (int i = 0; i < 8; ++i) acc[i] = (f32x4){0.f, 0.f, 0.f, 0.f};

    #pragma unroll
    for (int kk = 0; kk < 8; ++kk) {
        bf16x8 af = *(const bf16x8*)&As[arow][kk * 32 + ko];
        #pragma unroll
        for (int ct = 0; ct < 8; ++ct) {
            const unsigned short* wp = Wb + (ct * 16 + ncol) * 256 + kk * 32 + ko;
            bf16x8 bf = *(const bf16x8*)wp;
            acc[ct] = __builtin_amdgcn_mfma_f32_16x16x32_bf16(af, bf, acc[ct], 0, 0, 0);
        }
    }

    const int mr = rowBase + w * 16 + (lane >> 4) * 4;
    if (OUT_BF16) {
        unsigned short* out = (unsigned short*)out_v;
        #pragma unroll
        for (int ct = 0; ct < 8; ++ct) {
            #pragma unroll
            for (int r = 0; r < 4; ++r) {
                out[(size_t)(mr + r) * 128 + ct * 16 + ncol] = f2bf(fmaxf(acc[ct][r], 0.f));
            }
        }
    } else {
        float* out = (float*)out_v;
        #pragma unroll
        for (int ct = 0; ct < 8; ++ct) {
            #pragma unroll
            for (int r = 0; r < 4; ++r) {
                out[(size_t)(mr + r) * 128 + ct * 16 + ncol] = fmaxf(acc[ct][r], 0.f);
            }
        }
    }
}

extern "C" void kernel_launch(void* const* d_in, const int* in_sizes, int n_in,
                              void* d_out, int out_size, void* d_ws, size_t ws_size,
                              hipStream_t stream) {
    const float* raw   = (const float*)d_in[0];   // [200000,128]
    const float* W1    = (const float*)d_in[1];   // [128,256]
    const float* W2    = (const float*)d_in[2];   // [128,256]
    const int* self1   = (const int*)d_in[3];     // [81920]
    const int* neigh1  = (const int*)d_in[4];     // [81920,10]
    const int* self2   = (const int*)d_in[5];     // [8192]
    const int* neigh2  = (const int*)d_in[6];     // [8192,10]
    float* out = (float*)d_out;                   // [8192,128] f32

    char* ws = (char*)d_ws;
    unsigned short* W1b  = (unsigned short*)ws;                        // 128*256
    unsigned short* W2b  = W1b + 128 * 256;                            // 128*256
    unsigned short* h1   = W2b + 128 * 256;                            // 81920*128
    unsigned short* rawb = h1 + (size_t)81920 * 128;                   // 200000*128
    const size_t need = (size_t)(128 * 256 * 2 + 81920 * 128 + (size_t)200000 * 128) * 2;

    cvt_fused<<<12628, 256, 0, stream>>>(raw, W1, W2, rawb, W1b, W2b);

    if (ws_size >= need) {
        sage_layer_dma<true><<<81920 / 16, 256, 0, stream>>>(
            rawb, W1b, self1, neigh1, (void*)h1);
        sage_layer_dma<false><<<8192 / 16, 256, 0, stream>>>(
            h1, W2b, self2, neigh2, (void*)out);
    } else {
        sage_layer<false, true><<<81920 / 64, 256, 0, stream>>>(
            (const void*)raw, W1b, self1, neigh1, (void*)h1);
        sage_layer<true, false><<<8192 / 64, 256, 0, stream>>>(
            (const void*)h1, W2b, self2, neigh2, (void*)out);
    }
}